// Round 8
// baseline (173.236 us; speedup 1.0000x reference)
//
#include <hip/hip_runtime.h>

// ---------------------------------------------------------------------------
// HilbertAttention: fused cast -> fused {Q-proj | dilation-packed KV-proj}
// -> segmented attention -> out-proj.  B=4, M=4096, D=1024, H=16, hd=64,
// SEG=128, DIL=2 -> S=32. perm = closed-form serpentine (g==64).
// GEMM: 256x256 tile, BK=64, 8 waves (4Mx2N, per-wave 64x128), 4 phases per
// K-tile. ALL MFMA operands are ds_read >=1 phase before use; counted
// lgkmcnt(N) per phase (DS in-order) + sched_barrier(0); counted vmcnt(4/2)
// per K-tile (never 0 in steady loop). A frags double-set by tile parity
// (aEv/aOd); B quadrant frags ping-pong (bS0/bS1).
// R8 fix: B quadrant stride is 32 rows = 2048 halves (was 4096 -> OOB reads).
// ---------------------------------------------------------------------------

typedef _Float16 f16x8 __attribute__((ext_vector_type(8)));
typedef _Float16 f16x4 __attribute__((ext_vector_type(4)));
typedef float f32x4 __attribute__((ext_vector_type(4)));

__device__ __forceinline__ int hperm(int i) {
  int r = i >> 6, c = i & 63;
  return (r << 6) | ((r & 1) ? (63 - c) : c);
}
__device__ __forceinline__ int arow_gather(int mp) {
  int b = mp >> 11, i = mp & 2047;
  int s = i >> 6, j = i & 63;
  return b * 4096 + hperm(s * 128 + 2 * j);
}
__device__ __forceinline__ void gload_lds16(const _Float16* g, _Float16* l) {
  __builtin_amdgcn_global_load_lds(
      (const __attribute__((address_space(1))) void*)g,
      (__attribute__((address_space(3))) void*)l, 16, 0, 0);
}

// -------------------- fused cast fp32 -> fp16 (grid-stride) ----------------
__global__ __launch_bounds__(256) void cast_all(
    const float* __restrict__ x, _Float16* __restrict__ xh,
    const float* __restrict__ wq, _Float16* __restrict__ wqh,
    const float* __restrict__ wo, _Float16* __restrict__ woh) {
  for (int i = blockIdx.x * 256 + threadIdx.x; i < 5242880; i += 256 * 2048) {
    const float* s;
    _Float16* d;
    int j;
    if (i < 4194304) {
      s = x; d = xh; j = i;
    } else if (i < 4980736) {
      s = wq; d = wqh; j = i - 4194304;
    } else {
      s = wo; d = woh; j = i - 4980736;
    }
    float4 v = ((const float4*)s)[j];
    f16x4 o;
    o[0] = (_Float16)v.x;
    o[1] = (_Float16)v.y;
    o[2] = (_Float16)v.z;
    o[3] = (_Float16)v.w;
    *(f16x4*)&d[(size_t)j * 4] = o;
  }
}

// ------------------------- GEMM schedule macros ----------------------------
#define BAR __builtin_amdgcn_s_barrier()
#define SB0 __builtin_amdgcn_sched_barrier(0)
#define LGKM_(n)                                                  \
  do {                                                            \
    asm volatile("s_waitcnt lgkmcnt(" #n ")" ::: "memory");       \
    SB0;                                                          \
  } while (0)
#define VM4 asm volatile("s_waitcnt vmcnt(4)" ::: "memory")
#define VM2 asm volatile("s_waitcnt vmcnt(2)" ::: "memory")
#define VM0 asm volatile("s_waitcnt vmcnt(0)" ::: "memory")
#define VMX

// ds_read of A frag set half (ks) for one buffer
#define RDA(dst, bi, ks)                                       \
  _Pragma("unroll") for (int m = 0; m < 4; m++) dst[ks][m] =   \
      *(const f16x8*)(aRd[bi][ks] + m * 1024);
// ds_read of one B quadrant (32 N-rows = 2048 halves; 2 frags x 2 k-halves)
#define RDB(dst, bi, q)                                                     \
  _Pragma("unroll") for (int ks = 0; ks < 2; ks++)                          \
      _Pragma("unroll") for (int nf = 0; nf < 2; nf++) dst[ks][nf] =        \
          *(const f16x8*)(bRd[bi][ks] + (q)*2048 + nf * 1024);

#define SA(kt, buf, h)                                                        \
  do {                                                                        \
    gload_lds16(Ab + aOff[(h)*2] + (kt)*64, &lds[buf][0][(h)*8192 + t8]);     \
    gload_lds16(Ab + aOff[(h)*2 + 1] + (kt)*64,                               \
                &lds[buf][0][(h)*8192 + 4096 + t8]);                          \
  } while (0)
#define SBt(kt, buf, h)                                                       \
  do {                                                                        \
    gload_lds16(Bb + bOff[(h)*2] + (kt)*64, &lds[buf][1][(h)*8192 + t8]);     \
    gload_lds16(Bb + bOff[(h)*2 + 1] + (kt)*64,                               \
                &lds[buf][1][(h)*8192 + 4096 + t8]);                          \
  } while (0)

#define MMQ(AC, BS, q)                                                      \
  __builtin_amdgcn_s_setprio(1);                                            \
  _Pragma("unroll") for (int m = 0; m < 4; m++)                             \
      _Pragma("unroll") for (int nf = 0; nf < 2; nf++)                      \
          _Pragma("unroll") for (int ks = 0; ks < 2; ks++) acc[m][2 * (q) + \
                                                               nf] =        \
              __builtin_amdgcn_mfma_f32_16x16x32_f16(                       \
                  AC[ks][m], BS[ks][nf], acc[m][2 * (q) + nf], 0, 0, 0);    \
  __builtin_amdgcn_s_setprio(0);

// One K-tile (4 phases). P=T&1. AN = a-set for T+1, AC = a-set for T.
#define KT(P, T, RD_A, S1, S2, S3, VQ2, VQ3, RD_B0, AN, AC, LGA, LGB3) \
  do {                                                                 \
    /* q0 */                                                           \
    if (RD_A) { RDA(AN, (P) ^ 1, 0); }                                 \
    RDB(bS1, (P), 1);                                                  \
    if (S1) { SBt((T) + 1, (P) ^ 1, 1); }                              \
    BAR; LGKM_(LGA); MMQ(AC, bS0, 0);                                  \
    /* q1 */                                                           \
    if (RD_A) { RDA(AN, (P) ^ 1, 1); }                                 \
    RDB(bS0, (P), 2);                                                  \
    if (S2) { SA((T) + 2, (P), 0); }                                   \
    BAR; LGKM_(LGA); MMQ(AC, bS1, 1);                                  \
    /* q2 */                                                           \
    RDB(bS1, (P), 3);                                                  \
    if (S2) { SA((T) + 2, (P), 1); }                                   \
    VQ2; BAR; LGKM_(4); MMQ(AC, bS0, 2);                               \
    /* q3 */                                                           \
    if (RD_B0) { RDB(bS0, (P) ^ 1, 0); }                               \
    if (S3) { SBt((T) + 2, (P), 0); }                                  \
    VQ3; BAR; LGKM_(LGB3); MMQ(AC, bS1, 3);                            \
  } while (0)

template <typename OutT>
__device__ __forceinline__ void gemm_body(
    const _Float16* __restrict__ Ab, const _Float16* __restrict__ Bb,
    const unsigned* aOff, const unsigned* bOff, OutT* __restrict__ C, int N,
    size_t arow0, size_t bcol0, _Float16 (&lds)[2][2][16384]) {
  const int t = threadIdx.x;
  const int lane = t & 63, wave = t >> 6;
  const int wm = wave >> 1, wn = wave & 1;  // 4M x 2N; per-wave 64x128
  const int lr = lane & 15, lg = lane >> 4;
  const int t8 = t * 8;

  const int cx0 = (lg * 8) ^ ((lr & 7) << 3);
  const int cx1 = cx0 ^ 32;
  const _Float16* aRd[2][2];
  const _Float16* bRd[2][2];
#pragma unroll
  for (int bf = 0; bf < 2; bf++) {
    aRd[bf][0] = &lds[bf][0][(wm * 64 + lr) * 64 + cx0];
    aRd[bf][1] = &lds[bf][0][(wm * 64 + lr) * 64 + cx1];
    bRd[bf][0] = &lds[bf][1][(wn * 128 + lr) * 64 + cx0];
    bRd[bf][1] = &lds[bf][1][(wn * 128 + lr) * 64 + cx1];
  }

  f32x4 acc[4][8] = {};
  f16x8 aEv[2][4], aOd[2][4], bS0[2][2], bS1[2][2];

  // ---- prologue ----
  SA(0, 0, 0); SA(0, 0, 1); SBt(0, 0, 0); SBt(0, 0, 1);  // tile0 -> buf0 (8)
  SA(1, 1, 0); SA(1, 1, 1);                              // A(1) -> buf1 (4)
  VM4;  // drain tile0's 8
  BAR;
  RDA(aEv, 0, 0); RDA(aEv, 0, 1); RDB(bS0, 0, 0);        // a(0), b_0(0)
  SBt(1, 1, 0);                                          // B(1)h0 -> buf1 (2)
  VM2;  // drain A(1), leave B(1)h0 in flight
  BAR;

  // ---- steady: T=0..13 ----
  for (int i = 0; i < 7; i++) {
    KT(0, 2 * i,     1, 1, 1, 1, VM4, VM2, 1, aOd, aEv, 8, 4);
    KT(1, 2 * i + 1, 1, 1, 1, 1, VM4, VM2, 1, aEv, aOd, 8, 4);
  }
  // ---- tail: T=14 (drain all), T=15 (compute only) ----
  KT(0, 14, 1, 1, 0, 0, VM0, VMX, 1, aOd, aEv, 8, 4);
  KT(1, 15, 0, 0, 0, 0, VMX, VMX, 0, aEv, aOd, 4, 0);

  // ---- epilogue: C/D layout col=lane&15, row=(lane>>4)*4+j ----
#pragma unroll
  for (int m = 0; m < 4; m++) {
    size_t row0 = arow0 + wm * 64 + m * 16 + lg * 4;
#pragma unroll
    for (int n = 0; n < 8; n++) {
      size_t col = bcol0 + wn * 128 + (n >> 1) * 32 + (n & 1) * 16 + lr;
#pragma unroll
      for (int j = 0; j < 4; j++)
        C[(row0 + j) * N + col] = (OutT)acc[m][n][j];
    }
  }
}

// ---- fused Q-proj (sw<256) + KV-proj (sw>=256) over a 512-wg grid ----
__global__ __launch_bounds__(512, 2) void gemm_qkv(
    const _Float16* __restrict__ xh, const _Float16* __restrict__ wqh,
    _Float16* __restrict__ qh, _Float16* __restrict__ kvh) {
  __shared__ _Float16 lds[2][2][16384];
  const int t = threadIdx.x;
  const int id = blockIdx.x;
  const int sw = (id & 7) * (gridDim.x >> 3) + (id >> 3);
  const bool iskv = sw >= 256;
  const int wid = iskv ? sw - 256 : sw;
  const int N = iskv ? 2048 : 1024;
  const int bn = iskv ? (wid & 7) : (wid & 3);
  const int bm = iskv ? (wid >> 3) : (wid >> 2);
  const _Float16* Bb = wqh + (iskv ? (size_t)1048576 : 0);
  _Float16* C = iskv ? kvh : qh;

  const int sgrow = t >> 3;
  const int sgcol = ((t & 7) * 8) ^ ((sgrow & 7) << 3);
  unsigned aOff[4], bOff[4];
#pragma unroll
  for (int r = 0; r < 4; r++) {
    int mr = bm * 256 + 64 * r + sgrow;
    int ar = iskv ? arow_gather(mr) : mr;
    aOff[r] = (unsigned)ar * 1024u + (unsigned)sgcol;
    bOff[r] = ((unsigned)(bn * 256 + 64 * r + sgrow)) * 1024u + (unsigned)sgcol;
  }
  gemm_body<_Float16>(xh, Bb, aOff, bOff, C, N, (size_t)bm * 256,
                      (size_t)bn * 256, lds);
}

// ---- out-proj: 16384 x 1024 x 1024, fp32 output ----
__global__ __launch_bounds__(512, 2) void gemm_out(
    const _Float16* __restrict__ atth, const _Float16* __restrict__ woh,
    float* __restrict__ out) {
  __shared__ _Float16 lds[2][2][16384];
  const int t = threadIdx.x;
  const int id = blockIdx.x;
  const int sw = (id & 7) * (gridDim.x >> 3) + (id >> 3);
  const int bn = sw & 3, bm = sw >> 2;

  const int sgrow = t >> 3;
  const int sgcol = ((t & 7) * 8) ^ ((sgrow & 7) << 3);
  unsigned aOff[4], bOff[4];
#pragma unroll
  for (int r = 0; r < 4; r++) {
    aOff[r] = ((unsigned)(bm * 256 + 64 * r + sgrow)) * 1024u + (unsigned)sgcol;
    bOff[r] = ((unsigned)(bn * 256 + 64 * r + sgrow)) * 1024u + (unsigned)sgcol;
  }
  gemm_body<float>(atth, woh, aOff, bOff, out, 1024, (size_t)bm * 256,
                   (size_t)bn * 256, lds);
}

// ----------------------------- attention -----------------------------------
// One block per (b,h,s). Q gathered from qh via perm; K,V read CONTIGUOUSLY
// from the dilation-packed kvh[b*2048 + s*64 + j][2048].
#define STRD 72

__global__ __launch_bounds__(256) void hilbert_attn(
    const _Float16* __restrict__ qh, const _Float16* __restrict__ kvh,
    _Float16* __restrict__ aout) {
  __shared__ _Float16 Qs[128 * STRD];
  __shared__ _Float16 Ks[64 * STRD];
  __shared__ _Float16 Vt[64 * STRD];  // transposed: Vt[d][j] = V[j][d]
  __shared__ _Float16 Ps[128 * STRD];
  const int blk = blockIdx.x;
  const int s = blk & 31, h = (blk >> 5) & 15, b = blk >> 9;
  const int t = threadIdx.x, lane = t & 63, wave = t >> 6;
  const int lr = lane & 15, lg = lane >> 4, lk = lg * 8;
  const int col = (t & 7) * 8, rr = t >> 3;
  const size_t kvb = ((size_t)b * 2048 + s * 64) * 2048;

#pragma unroll
  for (int i = 0; i < 4; i++) {
    int m = i * 32 + rr;
    int p = b * 4096 + hperm(s * 128 + m);
    *(f16x8*)&Qs[m * STRD + col] =
        *(const f16x8*)&qh[(size_t)p * 1024 + h * 64 + col];
  }
#pragma unroll
  for (int i = 0; i < 2; i++) {
    int j = i * 32 + rr;
    *(f16x8*)&Ks[j * STRD + col] =
        *(const f16x8*)&kvh[kvb + (size_t)j * 2048 + h * 64 + col];
    f16x8 vv =
        *(const f16x8*)&kvh[kvb + (size_t)j * 2048 + 1024 + h * 64 + col];
#pragma unroll
    for (int e = 0; e < 8; e++) Vt[(col + e) * STRD + j] = vv[e];
  }
  __syncthreads();

  f32x4 accs[2][4] = {};
#pragma unroll
  for (int kk = 0; kk < 2; kk++) {
    f16x8 aa[2], bb[4];
#pragma unroll
    for (int m = 0; m < 2; m++)
      aa[m] = *(const f16x8*)&Qs[(wave * 32 + m * 16 + lr) * STRD + kk * 32 + lk];
#pragma unroll
    for (int n = 0; n < 4; n++)
      bb[n] = *(const f16x8*)&Ks[(n * 16 + lr) * STRD + kk * 32 + lk];
#pragma unroll
    for (int m = 0; m < 2; m++)
#pragma unroll
      for (int n = 0; n < 4; n++)
        accs[m][n] =
            __builtin_amdgcn_mfma_f32_16x16x32_f16(aa[m], bb[n], accs[m][n], 0, 0, 0);
  }

#pragma unroll
  for (int m = 0; m < 2; m++) {
#pragma unroll
    for (int j = 0; j < 4; j++) {
      float sc0 = accs[m][0][j] * 0.125f;
      float sc1 = accs[m][1][j] * 0.125f;
      float sc2 = accs[m][2][j] * 0.125f;
      float sc3 = accs[m][3][j] * 0.125f;
      float mx = fmaxf(fmaxf(sc0, sc1), fmaxf(sc2, sc3));
#pragma unroll
      for (int d = 1; d < 16; d <<= 1) mx = fmaxf(mx, __shfl_xor(mx, d, 16));
      float e0 = __expf(sc0 - mx), e1 = __expf(sc1 - mx);
      float e2 = __expf(sc2 - mx), e3 = __expf(sc3 - mx);
      float sum = (e0 + e1) + (e2 + e3);
#pragma unroll
      for (int d = 1; d < 16; d <<= 1) sum += __shfl_xor(sum, d, 16);
      float inv = 1.0f / sum;
      int row = wave * 32 + m * 16 + lg * 4 + j;
      Ps[row * STRD + 0 * 16 + lr] = (_Float16)(e0 * inv);
      Ps[row * STRD + 1 * 16 + lr] = (_Float16)(e1 * inv);
      Ps[row * STRD + 2 * 16 + lr] = (_Float16)(e2 * inv);
      Ps[row * STRD + 3 * 16 + lr] = (_Float16)(e3 * inv);
    }
  }
  __syncthreads();

  f32x4 acco[2][4] = {};
#pragma unroll
  for (int kk = 0; kk < 2; kk++) {
    f16x8 aa[2], bb[4];
#pragma unroll
    for (int m = 0; m < 2; m++)
      aa[m] = *(const f16x8*)&Ps[(wave * 32 + m * 16 + lr) * STRD + kk * 32 + lk];
#pragma unroll
    for (int n = 0; n < 4; n++)
      bb[n] = *(const f16x8*)&Vt[(n * 16 + lr) * STRD + kk * 32 + lk];
#pragma unroll
    for (int m = 0; m < 2; m++)
#pragma unroll
      for (int n = 0; n < 4; n++)
        acco[m][n] =
            __builtin_amdgcn_mfma_f32_16x16x32_f16(aa[m], bb[n], acco[m][n], 0, 0, 0);
  }

  const size_t orow0 = (size_t)b * 4096 + s * 128;
#pragma unroll
  for (int m = 0; m < 2; m++) {
#pragma unroll
    for (int n = 0; n < 4; n++) {
#pragma unroll
      for (int j = 0; j < 4; j++) {
        size_t row = orow0 + wave * 32 + m * 16 + lg * 4 + j;
        aout[row * 1024 + h * 64 + n * 16 + lr] = (_Float16)acco[m][n][j];
      }
    }
  }
}

// ---------------------------------------------------------------------------
extern "C" void kernel_launch(void* const* d_in, const int* in_sizes, int n_in,
                              void* d_out, int out_size, void* d_ws, size_t ws_size,
                              hipStream_t stream) {
  const float* x = (const float*)d_in[0];      // (4,4096,1024)
  const float* w_qkv = (const float*)d_in[1];  // (3072,1024)
  const float* w_out = (const float*)d_in[2];  // (1024,1024)
  float* out = (float*)d_out;                  // (4,4096,1024) fp32
  char* ws = (char*)d_ws;

  _Float16* xh = (_Float16*)(ws + 0);                    // 33,554,432 B
  _Float16* wqh = (_Float16*)(ws + (size_t)33554432);    //  6,291,456 B
  _Float16* woh = (_Float16*)(ws + (size_t)39845888);    //  2,097,152 B
  _Float16* qh = (_Float16*)(ws + (size_t)41943040);     // 33,554,432 B
  _Float16* kvh = (_Float16*)(ws + (size_t)75497472);    // 33,554,432 B
  _Float16* atth = (_Float16*)(ws + (size_t)109051904);  // 33,554,432 B

  cast_all<<<2048, 256, 0, stream>>>(x, xh, w_qkv, wqh, w_out, woh);

  // fused Q-proj (256 wg: 64x4) + KV-proj (256 wg: 32x8)
  gemm_qkv<<<512, 512, 0, stream>>>(xh, wqh, qh, kvh);
  hilbert_attn<<<2048, 256, 0, stream>>>(qh, kvh, atth);
  gemm_out<<<256, 512, 0, stream>>>(atth, woh, out);
}